// Round 21
// baseline (142.250 us; speedup 1.0000x reference)
//
#include <hip/hip_runtime.h>
#include <math.h>

#define C 128
#define SLOTS 16     // per-row edge slots; P(deg>16) ~ 1e-5, overflow list catches the rest
#define OVFCAP 8192
#define DSTRIDE 132  // padded f32 LDS row stride for GEMM output

typedef __attribute__((ext_vector_type(8))) short short8;
typedef __attribute__((ext_vector_type(4))) float f32x4;
typedef __attribute__((ext_vector_type(2))) float f32x2;
typedef __attribute__((ext_vector_type(8))) unsigned short ushort8_t;

__device__ inline unsigned short f2b(float f) {
    union { float f; unsigned int u; } v; v.f = f;
    unsigned int u = v.u;
    return (unsigned short)((u + 0x7FFFu + ((u >> 16) & 1u)) >> 16);  // RNE
}
__device__ inline float bits2f(unsigned int u) {
    union { unsigned int u; float f; } v; v.u = u; return v.f;
}
__device__ inline int f2bits(float f) {
    union { float f; int i; } v; v.f = f; return v.i;
}

// accumulate 8 bf16 (packed in uint4) scaled by s into a[0..3] (f32x2 pairs)
__device__ inline void acc8(f32x2* a, uint4 u, f32x2 s) {
    f32x2 v0 = {bits2f(u.x << 16), bits2f(u.x & 0xFFFF0000u)};
    f32x2 v1 = {bits2f(u.y << 16), bits2f(u.y & 0xFFFF0000u)};
    f32x2 v2 = {bits2f(u.z << 16), bits2f(u.z & 0xFFFF0000u)};
    f32x2 v3 = {bits2f(u.w << 16), bits2f(u.w & 0xFFFF0000u)};
    a[0] += s * v0;
    a[1] += s * v1;
    a[2] += s * v2;
    a[3] += s * v3;
}

__device__ inline void place_edge(int d, int slot, int s, int wbits,
                                  int2* __restrict__ eslot, int* __restrict__ ovfcnt,
                                  int4* __restrict__ ovf) {
    if (slot < SLOTS) {
        eslot[(size_t)d * SLOTS + slot] = make_int2(s, wbits);
    } else {
        int oi = atomicAdd(ovfcnt, 1);
        if (oi < OVFCAP) ovf[oi] = make_int4(d, s, wbits, 0);
    }
}

// ============ single prep kernel: edges FIRST (atomic-bound), then W-pack, then convert ===
__global__ void k_place_cvt_pack(const int* __restrict__ src, const int* __restrict__ dst,
                                 const float* __restrict__ ew,
                                 int* __restrict__ cnt, int* __restrict__ ovfcnt,
                                 int2* __restrict__ eslot, int4* __restrict__ ovf,
                                 int e, int ge4,
                                 const float* __restrict__ x, unsigned short* __restrict__ xb,
                                 int ncvt8,
                                 const float* __restrict__ W1, const float* __restrict__ W2,
                                 unsigned short* __restrict__ W1p,
                                 unsigned short* __restrict__ W2p) {
    const int bid = blockIdx.x;
    const int tid = threadIdx.x;
    if (bid < ge4) {
        const int i0 = bid * 1024 + tid * 4;
        if (((e & 3) == 0) && (i0 + 3 < e)) {
            int4 s4 = *(const int4*)(src + i0);
            int4 d4 = *(const int4*)(dst + i0);
            float4 w4 = *(const float4*)(ew + i0);
            int sl0 = atomicAdd(&cnt[d4.x], 1);
            int sl1 = atomicAdd(&cnt[d4.y], 1);
            int sl2 = atomicAdd(&cnt[d4.z], 1);
            int sl3 = atomicAdd(&cnt[d4.w], 1);
            place_edge(d4.x, sl0, s4.x, f2bits(w4.x), eslot, ovfcnt, ovf);
            place_edge(d4.y, sl1, s4.y, f2bits(w4.y), eslot, ovfcnt, ovf);
            place_edge(d4.z, sl2, s4.z, f2bits(w4.z), eslot, ovfcnt, ovf);
            place_edge(d4.w, sl3, s4.w, f2bits(w4.w), eslot, ovfcnt, ovf);
        } else {
            #pragma unroll
            for (int k = 0; k < 4; ++k) {
                int i = i0 + k;
                if (i < e) {
                    int s = src[i], d = dst[i];
                    int slot = atomicAdd(&cnt[d], 1);
                    place_edge(d, slot, s, f2bits(ew[i]), eslot, ovfcnt, ovf);
                }
            }
        }
        return;
    }
    if (bid < ge4 + 128) {                         // weight pack: 128 blocks x 256
        int idx = (bid - ge4) * 256 + tid;         // 0 .. 2*C*C-1
        const float* W = (idx < C * C) ? W1 : W2;
        unsigned short* Wp = (idx < C * C) ? W1p : W2p;
        int p = idx & (C * C - 1);
        int j = p & 7;
        int l = (p >> 3) & 63;
        int t = p >> 9;           // ct*4 + ks
        int ks = t & 3, ct = t >> 2;
        int k = ks * 32 + ((l >> 4) << 3) + j;
        int c = (ct << 4) + (l & 15);
        Wp[p] = f2b(W[k * C + c]);
        return;
    }
    int i = (bid - ge4 - 128) * 256 + tid;
    if (i < ncvt8) {
        const float4* xp = (const float4*)(x + (size_t)i * 8);
        float4 v0 = xp[0];
        float4 v1 = xp[1];
        ushort8_t pkt;
        pkt[0] = f2b(v0.x); pkt[1] = f2b(v0.y); pkt[2] = f2b(v0.z); pkt[3] = f2b(v0.w);
        pkt[4] = f2b(v1.x); pkt[5] = f2b(v1.y); pkt[6] = f2b(v1.z); pkt[7] = f2b(v1.w);
        *(ushort8_t*)(xb + (size_t)i * 8) = pkt;
    }
}

// ========== layer kernel: agg(Xin) -> @W -> +bias -> LN -> GELU [-> +resid] ==========
// 512 threads, 32 rows/block. agg(X@W) == agg(X)@W. Fixed-slot CSR.
// raw_w==1 (layer 1): slot weight = raw ew bits; compute w = rsqrt(cnt[s]+1)*ew*dis[d]
//   on the fly AND write the final w back into eslot (own window only — no race).
// raw_w==0 (layer 2): slot weight is already final; no cnt gathers.
__global__ __launch_bounds__(512) void k_layer(
    const int* __restrict__ cnt, const int* __restrict__ ovfcnt,
    int2* __restrict__ eslot, const int4* __restrict__ ovf,
    const unsigned short* __restrict__ Xin,
    const unsigned short* __restrict__ Wp,
    const float* __restrict__ bias, const float* __restrict__ g,
    const float* __restrict__ beta,
    const unsigned short* __restrict__ xb_resid,
    unsigned short* __restrict__ out_bf16, float* __restrict__ out_f32,
    int n, int raw_w) {
    __shared__ int2 eds[32 * SLOTS];           // 4 KB (one int2 per thread)
    __shared__ unsigned short xs[32 * C];      // 8 KB, XOR-swizzled (GEMM A input)
    __shared__ float dacc[32 * DSTRIDE];       // 16.9 KB (GEMM output rows)
    const int tid = threadIdx.x;
    const int lane = tid & 63;
    const int wid = tid >> 6;           // 0..7
    const int grp = lane >> 4;          // 0..3
    const int sub = lane & 15;
    const int base = blockIdx.x * 32;
    const int c0 = sub * 8;

    // stage this block's slot window (fixed 512 slots)
    {
        size_t gi = (size_t)base * SLOTS + tid;
        eds[tid] = (gi < (size_t)n * SLOTS) ? eslot[gi] : make_int2(0, 0);
    }
    __syncthreads();

    // phase A: aggregate 32 rows (1 row per 16-lane group), pack bf16 into swizzled LDS
    {
        int r = wid * 4 + grp;          // 0..31
        int row = base + r;
        f32x2 a[4] = {f32x2{0.f, 0.f}, f32x2{0.f, 0.f}, f32x2{0.f, 0.f}, f32x2{0.f, 0.f}};
        if (row < n) {
            int cd = cnt[row];
            float disr = rsqrtf((float)cd + 1.0f);
            // self-loop: dis^2 * Xin[row]
            {
                f32x2 d2 = {disr * disr, disr * disr};
                uint4 hu = *(const uint4*)(Xin + (size_t)row * C + c0);
                acc8(a, hu, d2);
            }
            const int kb = r * SLOTS;
            const int ke = kb + (cd < SLOTS ? cd : SLOTS);
            int k = kb;
            if (raw_w) {
                for (; k + 3 < ke; k += 4) {
                    int2 e0 = eds[k];
                    int2 e1 = eds[k + 1];
                    int2 e2 = eds[k + 2];
                    int2 e3 = eds[k + 3];
                    int cs0 = cnt[e0.x];
                    int cs1 = cnt[e1.x];
                    int cs2 = cnt[e2.x];
                    int cs3 = cnt[e3.x];
                    uint4 u0 = *(const uint4*)(Xin + (size_t)e0.x * C + c0);
                    uint4 u1 = *(const uint4*)(Xin + (size_t)e1.x * C + c0);
                    uint4 u2 = *(const uint4*)(Xin + (size_t)e2.x * C + c0);
                    uint4 u3 = *(const uint4*)(Xin + (size_t)e3.x * C + c0);
                    float w0 = rsqrtf((float)cs0 + 1.0f) * bits2f((unsigned int)e0.y) * disr;
                    float w1 = rsqrtf((float)cs1 + 1.0f) * bits2f((unsigned int)e1.y) * disr;
                    float w2 = rsqrtf((float)cs2 + 1.0f) * bits2f((unsigned int)e2.y) * disr;
                    float w3 = rsqrtf((float)cs3 + 1.0f) * bits2f((unsigned int)e3.y) * disr;
                    if (sub == 0) {   // one lane per group patches the final weights
                        size_t gk = (size_t)base * SLOTS + k;
                        ((int*)eslot)[gk * 2 + 1] = f2bits(w0);
                        ((int*)eslot)[gk * 2 + 3] = f2bits(w1);
                        ((int*)eslot)[gk * 2 + 5] = f2bits(w2);
                        ((int*)eslot)[gk * 2 + 7] = f2bits(w3);
                    }
                    acc8(a, u0, f32x2{w0, w0});
                    acc8(a, u1, f32x2{w1, w1});
                    acc8(a, u2, f32x2{w2, w2});
                    acc8(a, u3, f32x2{w3, w3});
                }
                for (; k < ke; ++k) {
                    int2 e0 = eds[k];
                    int cs0 = cnt[e0.x];
                    uint4 u0 = *(const uint4*)(Xin + (size_t)e0.x * C + c0);
                    float w0 = rsqrtf((float)cs0 + 1.0f) * bits2f((unsigned int)e0.y) * disr;
                    if (sub == 0) {
                        size_t gk = (size_t)base * SLOTS + k;
                        ((int*)eslot)[gk * 2 + 1] = f2bits(w0);
                    }
                    acc8(a, u0, f32x2{w0, w0});
                }
            } else {
                for (; k + 3 < ke; k += 4) {
                    int2 e0 = eds[k];
                    int2 e1 = eds[k + 1];
                    int2 e2 = eds[k + 2];
                    int2 e3 = eds[k + 3];
                    uint4 u0 = *(const uint4*)(Xin + (size_t)e0.x * C + c0);
                    uint4 u1 = *(const uint4*)(Xin + (size_t)e1.x * C + c0);
                    uint4 u2 = *(const uint4*)(Xin + (size_t)e2.x * C + c0);
                    uint4 u3 = *(const uint4*)(Xin + (size_t)e3.x * C + c0);
                    float w0 = bits2f((unsigned int)e0.y);
                    float w1 = bits2f((unsigned int)e1.y);
                    float w2 = bits2f((unsigned int)e2.y);
                    float w3 = bits2f((unsigned int)e3.y);
                    acc8(a, u0, f32x2{w0, w0});
                    acc8(a, u1, f32x2{w1, w1});
                    acc8(a, u2, f32x2{w2, w2});
                    acc8(a, u3, f32x2{w3, w3});
                }
                for (; k < ke; ++k) {
                    int2 e0 = eds[k];
                    uint4 u0 = *(const uint4*)(Xin + (size_t)e0.x * C + c0);
                    float w0 = bits2f((unsigned int)e0.y);
                    acc8(a, u0, f32x2{w0, w0});
                }
            }
            // overflow edges (expected ~0-3 total per run): always compute from cnt
            int no = *ovfcnt;
            if (no > 0) {
                if (no > OVFCAP) no = OVFCAP;
                for (int oi = 0; oi < no; ++oi) {
                    int4 ov = ovf[oi];
                    if (ov.x == row) {
                        uint4 u0 = *(const uint4*)(Xin + (size_t)ov.y * C + c0);
                        float w0 = rsqrtf((float)cnt[ov.y] + 1.0f)
                                 * bits2f((unsigned int)ov.z) * disr;
                        acc8(a, u0, f32x2{w0, w0});
                    }
                }
            }
        }
        ushort8_t pkt;
        #pragma unroll
        for (int q = 0; q < 4; ++q) { pkt[q * 2] = f2b(a[q].x); pkt[q * 2 + 1] = f2b(a[q].y); }
        int byte = (r * 256 + c0 * 2) ^ ((r & 7) << 4);
        *(ushort8_t*)((char*)xs + byte) = pkt;
    }
    __syncthreads();

    // phase B: 8-wave MFMA GEMM (32x128) = xs @ Wp; write f32 + bias into dacc
    {
        const int wm = wid >> 2;        // 0..1 (row tile of 16)
        const int wn = wid & 3;         // 0..3 (col quarter of 32)
        const int arow = wm * 16 + (lane & 15);
        const int kg = lane >> 4;

        f32x4 acc[2] = {f32x4{0, 0, 0, 0}, f32x4{0, 0, 0, 0}};

        #pragma unroll
        for (int ks = 0; ks < 4; ++ks) {
            int abyte = (arow * 256 + ks * 64 + kg * 16) ^ ((arow & 7) << 4);
            short8 av = *(const short8*)((const char*)xs + abyte);
            #pragma unroll
            for (int nt = 0; nt < 2; ++nt) {
                int ct = wn * 2 + nt;
                short8 bv = *(const short8*)(Wp + (size_t)((ct * 4 + ks) * 64 + lane) * 8);
                acc[nt] = __builtin_amdgcn_mfma_f32_16x16x32_bf16(av, bv, acc[nt], 0, 0, 0);
            }
        }

        const int rb = wm * 16 + kg * 4;   // block-local output row base
        #pragma unroll
        for (int nt = 0; nt < 2; ++nt) {
            int col = wn * 32 + nt * 16 + (lane & 15);
            float bv = bias[col];
            #pragma unroll
            for (int r2 = 0; r2 < 4; ++r2)
                dacc[(rb + r2) * DSTRIDE + col] = acc[nt][r2] + bv;
        }
    }
    __syncthreads();

    // phase C: LN + GELU per row from dacc (16 lanes/row), then epilogue
    {
        int r = wid * 4 + grp;
        int row = base + r;
        if (row >= n) return;

        const float* dp = dacc + r * DSTRIDE + c0;
        float4 v0 = *(const float4*)(dp);
        float4 v1 = *(const float4*)(dp + 4);
        float a[8] = {v0.x, v0.y, v0.z, v0.w, v1.x, v1.y, v1.z, v1.w};

        float s = 0.f, sq = 0.f;
        #pragma unroll
        for (int j = 0; j < 8; ++j) { s += a[j]; sq += a[j] * a[j]; }
        #pragma unroll
        for (int off = 8; off >= 1; off >>= 1) {
            s  += __shfl_xor(s, off, 64);
            sq += __shfl_xor(sq, off, 64);
        }
        float mu = s * (1.0f / C);
        float var = sq * (1.0f / C) - mu * mu;
        float rstd = rsqrtf(var + 1e-5f);

        float4 gv0 = *(const float4*)(g + c0);
        float4 gv1 = *(const float4*)(g + c0 + 4);
        float4 be0 = *(const float4*)(beta + c0);
        float4 be1 = *(const float4*)(beta + c0 + 4);
        float gg[8] = {gv0.x, gv0.y, gv0.z, gv0.w, gv1.x, gv1.y, gv1.z, gv1.w};
        float bb[8] = {be0.x, be0.y, be0.z, be0.w, be1.x, be1.y, be1.z, be1.w};

        float t[8];
        #pragma unroll
        for (int j = 0; j < 8; ++j) {
            float v = (a[j] - mu) * rstd * gg[j] + bb[j];
            t[j] = 0.5f * v * (1.0f + erff(v * 0.70710678118654752f));
        }

        if (out_f32 != nullptr) {
            ushort8_t rv = *(const ushort8_t*)(xb_resid + (size_t)row * C + c0);
            #pragma unroll
            for (int j = 0; j < 8; ++j)
                t[j] += bits2f(((unsigned int)(unsigned short)rv[j]) << 16);
            *(float4*)(out_f32 + (size_t)row * C + c0) = make_float4(t[0], t[1], t[2], t[3]);
            *(float4*)(out_f32 + (size_t)row * C + c0 + 4) = make_float4(t[4], t[5], t[6], t[7]);
        } else {
            ushort8_t pkt;
            #pragma unroll
            for (int j = 0; j < 8; ++j) pkt[j] = f2b(t[j]);
            *(ushort8_t*)(out_bf16 + (size_t)row * C + c0) = pkt;
        }
    }
}

// ================= launch =================

extern "C" void kernel_launch(void* const* d_in, const int* in_sizes, int n_in,
                              void* d_out, int out_size, void* d_ws, size_t ws_size,
                              hipStream_t stream) {
    const float* x      = (const float*)d_in[0];
    const int*   eidx   = (const int*)d_in[1];
    const float* ew     = (const float*)d_in[2];
    const float* W1     = (const float*)d_in[3];
    const float* b1     = (const float*)d_in[4];
    const float* g1     = (const float*)d_in[5];
    const float* beta1  = (const float*)d_in[6];
    const float* W2     = (const float*)d_in[7];
    const float* b2     = (const float*)d_in[8];
    const float* g2     = (const float*)d_in[9];
    const float* beta2  = (const float*)d_in[10];

    const int n = in_sizes[0] / C;
    const int e = in_sizes[2];
    const int* src = eidx;
    const int* dst = eidx + e;

    float* out = (float*)d_out;

    // workspace layout (256B-aligned chunks)
    char* p = (char*)d_ws;
    auto alloc = [&](size_t bytes) {
        char* q = p;
        p += (bytes + 255) & ~(size_t)255;
        return q;
    };
    int*   cnt    = (int*)alloc(sizeof(int) * (n + 1));           // cnt[n] = overflow count
    int2*  eslot  = (int2*)alloc(sizeof(int2) * (size_t)n * SLOTS);
    int4*  ovf    = (int4*)alloc(sizeof(int4) * OVFCAP);
    unsigned short* xb    = (unsigned short*)alloc(sizeof(unsigned short) * (size_t)n * C);
    unsigned short* hact1 = (unsigned short*)alloc(sizeof(unsigned short) * (size_t)n * C);
    unsigned short* W1p   = (unsigned short*)alloc(sizeof(unsigned short) * C * C);
    unsigned short* W2p   = (unsigned short*)alloc(sizeof(unsigned short) * C * C);
    int* ovfcnt = cnt + n;

    const int B = 256;
    const int ge4 = (e + 1023) / 1024;    // edge blocks (4 edges/thread)
    const int ncvt8 = n * C / 8;          // 8-elem convert items
    const int bc = (ncvt8 + B - 1) / B;   // convert blocks

    // prep: zero counters; then ONE kernel: edges (atomic-bound, starts at t=0) ||
    // weight-pack || x->bf16 convert (BW-bound, fills remaining CUs)
    hipMemsetAsync(cnt, 0, sizeof(int) * (n + 1), stream);
    k_place_cvt_pack<<<ge4 + 128 + bc, B, 0, stream>>>(src, dst, ew, cnt, ovfcnt,
                                                       eslot, ovf, e, ge4,
                                                       x, xb, ncvt8,
                                                       W1, W2, W1p, W2p);

    // layer 1 (raw_w=1): hact1 = GELU(LN(agg(xb) @ W1 + b1)); patches final w into eslot
    k_layer<<<(n + 31) / 32, 512, 0, stream>>>(cnt, ovfcnt, eslot, ovf, xb, W1p,
                                               b1, g1, beta1, nullptr,
                                               hact1, nullptr, n, 1);

    // layer 2 (raw_w=0): out = GELU(LN(agg(hact1) @ W2 + b2)) + x; reads patched w
    k_layer<<<(n + 31) / 32, 512, 0, stream>>>(cnt, ovfcnt, eslot, ovf, hact1, W2p,
                                               b2, g2, beta2, xb,
                                               nullptr, out, n, 0);
}

// Round 22
// 138.262 us; speedup vs baseline: 1.0288x; 1.0288x over previous
//
#include <hip/hip_runtime.h>
#include <math.h>

#define C 128
#define SLOTS 16     // per-row edge slots; P(deg>16) ~ 1e-5, overflow list catches the rest
#define OVFCAP 8192
#define DSTRIDE 132  // padded f32 LDS row stride for GEMM output

typedef __attribute__((ext_vector_type(8))) short short8;
typedef __attribute__((ext_vector_type(4))) float f32x4;
typedef __attribute__((ext_vector_type(2))) float f32x2;
typedef __attribute__((ext_vector_type(8))) unsigned short ushort8_t;

__device__ inline unsigned short f2b(float f) {
    union { float f; unsigned int u; } v; v.f = f;
    unsigned int u = v.u;
    return (unsigned short)((u + 0x7FFFu + ((u >> 16) & 1u)) >> 16);  // RNE
}
__device__ inline float bits2f(unsigned int u) {
    union { unsigned int u; float f; } v; v.u = u; return v.f;
}
__device__ inline int f2bits(float f) {
    union { float f; int i; } v; v.f = f; return v.i;
}

// accumulate 8 bf16 (packed in uint4) scaled by s into a[0..3] (f32x2 pairs)
__device__ inline void acc8(f32x2* a, uint4 u, f32x2 s) {
    f32x2 v0 = {bits2f(u.x << 16), bits2f(u.x & 0xFFFF0000u)};
    f32x2 v1 = {bits2f(u.y << 16), bits2f(u.y & 0xFFFF0000u)};
    f32x2 v2 = {bits2f(u.z << 16), bits2f(u.z & 0xFFFF0000u)};
    f32x2 v3 = {bits2f(u.w << 16), bits2f(u.w & 0xFFFF0000u)};
    a[0] += s * v0;
    a[1] += s * v1;
    a[2] += s * v2;
    a[3] += s * v3;
}

__device__ inline void place_edge(int d, int slot, int s, int wbits,
                                  int2* __restrict__ eslot, int* __restrict__ ovfcnt,
                                  int4* __restrict__ ovf) {
    if (slot < SLOTS) {
        eslot[(size_t)d * SLOTS + slot] = make_int2(s, wbits);
    } else {
        int oi = atomicAdd(ovfcnt, 1);
        if (oi < OVFCAP) ovf[oi] = make_int4(d, s, wbits, 0);
    }
}

// ============ single prep kernel: edges FIRST (atomic-bound), then W-pack, then convert ===
__global__ void k_place_cvt_pack(const int* __restrict__ src, const int* __restrict__ dst,
                                 const float* __restrict__ ew,
                                 int* __restrict__ cnt, int* __restrict__ ovfcnt,
                                 int2* __restrict__ eslot, int4* __restrict__ ovf,
                                 int e, int ge4,
                                 const float* __restrict__ x, unsigned short* __restrict__ xb,
                                 int ncvt8,
                                 const float* __restrict__ W1, const float* __restrict__ W2,
                                 unsigned short* __restrict__ W1p,
                                 unsigned short* __restrict__ W2p) {
    const int bid = blockIdx.x;
    const int tid = threadIdx.x;
    if (bid < ge4) {
        const int i0 = bid * 1024 + tid * 4;
        if (((e & 3) == 0) && (i0 + 3 < e)) {
            int4 s4 = *(const int4*)(src + i0);
            int4 d4 = *(const int4*)(dst + i0);
            float4 w4 = *(const float4*)(ew + i0);
            int sl0 = atomicAdd(&cnt[d4.x], 1);
            int sl1 = atomicAdd(&cnt[d4.y], 1);
            int sl2 = atomicAdd(&cnt[d4.z], 1);
            int sl3 = atomicAdd(&cnt[d4.w], 1);
            place_edge(d4.x, sl0, s4.x, f2bits(w4.x), eslot, ovfcnt, ovf);
            place_edge(d4.y, sl1, s4.y, f2bits(w4.y), eslot, ovfcnt, ovf);
            place_edge(d4.z, sl2, s4.z, f2bits(w4.z), eslot, ovfcnt, ovf);
            place_edge(d4.w, sl3, s4.w, f2bits(w4.w), eslot, ovfcnt, ovf);
        } else {
            #pragma unroll
            for (int k = 0; k < 4; ++k) {
                int i = i0 + k;
                if (i < e) {
                    int s = src[i], d = dst[i];
                    int slot = atomicAdd(&cnt[d], 1);
                    place_edge(d, slot, s, f2bits(ew[i]), eslot, ovfcnt, ovf);
                }
            }
        }
        return;
    }
    if (bid < ge4 + 128) {                         // weight pack: 128 blocks x 256
        int idx = (bid - ge4) * 256 + tid;         // 0 .. 2*C*C-1
        const float* W = (idx < C * C) ? W1 : W2;
        unsigned short* Wp = (idx < C * C) ? W1p : W2p;
        int p = idx & (C * C - 1);
        int j = p & 7;
        int l = (p >> 3) & 63;
        int t = p >> 9;           // ct*4 + ks
        int ks = t & 3, ct = t >> 2;
        int k = ks * 32 + ((l >> 4) << 3) + j;
        int c = (ct << 4) + (l & 15);
        Wp[p] = f2b(W[k * C + c]);
        return;
    }
    int i = (bid - ge4 - 128) * 256 + tid;
    if (i < ncvt8) {
        const float4* xp = (const float4*)(x + (size_t)i * 8);
        float4 v0 = xp[0];
        float4 v1 = xp[1];
        ushort8_t pkt;
        pkt[0] = f2b(v0.x); pkt[1] = f2b(v0.y); pkt[2] = f2b(v0.z); pkt[3] = f2b(v0.w);
        pkt[4] = f2b(v1.x); pkt[5] = f2b(v1.y); pkt[6] = f2b(v1.z); pkt[7] = f2b(v1.w);
        *(ushort8_t*)(xb + (size_t)i * 8) = pkt;
    }
}

// ========== layer kernel: agg(Xin) -> @W -> +bias -> LN -> GELU [-> +resid] ==========
// 512 threads, 32 rows/block. agg(X@W) == agg(X)@W. Fixed-slot CSR; edge weight
// w = rsqrt(cnt[s]+1)*ew*rsqrt(cnt[d]+1) computed on the fly (cnt is L2-hot, 400 KB).
__global__ __launch_bounds__(512) void k_layer(
    const int* __restrict__ cnt, const int* __restrict__ ovfcnt,
    const int2* __restrict__ eslot, const int4* __restrict__ ovf,
    const unsigned short* __restrict__ Xin,
    const unsigned short* __restrict__ Wp,
    const float* __restrict__ bias, const float* __restrict__ g,
    const float* __restrict__ beta,
    const unsigned short* __restrict__ xb_resid,
    unsigned short* __restrict__ out_bf16, float* __restrict__ out_f32, int n) {
    __shared__ int2 eds[32 * SLOTS];           // 4 KB (one int2 per thread)
    __shared__ unsigned short xs[32 * C];      // 8 KB, XOR-swizzled (GEMM A input)
    __shared__ float dacc[32 * DSTRIDE];       // 16.9 KB (GEMM output rows)
    const int tid = threadIdx.x;
    const int lane = tid & 63;
    const int wid = tid >> 6;           // 0..7
    const int grp = lane >> 4;          // 0..3
    const int sub = lane & 15;
    const int base = blockIdx.x * 32;
    const int c0 = sub * 8;

    // stage this block's slot window (fixed 512 slots)
    {
        size_t gi = (size_t)base * SLOTS + tid;
        eds[tid] = (gi < (size_t)n * SLOTS) ? eslot[gi] : make_int2(0, 0);
    }
    __syncthreads();

    // phase A: aggregate 32 rows (1 row per 16-lane group), pack bf16 into swizzled LDS
    {
        int r = wid * 4 + grp;          // 0..31
        int row = base + r;
        f32x2 a[4] = {f32x2{0.f, 0.f}, f32x2{0.f, 0.f}, f32x2{0.f, 0.f}, f32x2{0.f, 0.f}};
        if (row < n) {
            int cd = cnt[row];
            float disr = rsqrtf((float)cd + 1.0f);
            // self-loop: dis^2 * Xin[row]
            {
                f32x2 d2 = {disr * disr, disr * disr};
                uint4 hu = *(const uint4*)(Xin + (size_t)row * C + c0);
                acc8(a, hu, d2);
            }
            const int kb = r * SLOTS;
            const int ke = kb + (cd < SLOTS ? cd : SLOTS);
            int k = kb;
            for (; k + 3 < ke; k += 4) {
                int2 e0 = eds[k];
                int2 e1 = eds[k + 1];
                int2 e2 = eds[k + 2];
                int2 e3 = eds[k + 3];
                int cs0 = cnt[e0.x];
                int cs1 = cnt[e1.x];
                int cs2 = cnt[e2.x];
                int cs3 = cnt[e3.x];
                uint4 u0 = *(const uint4*)(Xin + (size_t)e0.x * C + c0);
                uint4 u1 = *(const uint4*)(Xin + (size_t)e1.x * C + c0);
                uint4 u2 = *(const uint4*)(Xin + (size_t)e2.x * C + c0);
                uint4 u3 = *(const uint4*)(Xin + (size_t)e3.x * C + c0);
                float w0 = rsqrtf((float)cs0 + 1.0f) * bits2f((unsigned int)e0.y) * disr;
                float w1 = rsqrtf((float)cs1 + 1.0f) * bits2f((unsigned int)e1.y) * disr;
                float w2 = rsqrtf((float)cs2 + 1.0f) * bits2f((unsigned int)e2.y) * disr;
                float w3 = rsqrtf((float)cs3 + 1.0f) * bits2f((unsigned int)e3.y) * disr;
                acc8(a, u0, f32x2{w0, w0});
                acc8(a, u1, f32x2{w1, w1});
                acc8(a, u2, f32x2{w2, w2});
                acc8(a, u3, f32x2{w3, w3});
            }
            for (; k < ke; ++k) {
                int2 e0 = eds[k];
                int cs0 = cnt[e0.x];
                uint4 u0 = *(const uint4*)(Xin + (size_t)e0.x * C + c0);
                float w0 = rsqrtf((float)cs0 + 1.0f) * bits2f((unsigned int)e0.y) * disr;
                acc8(a, u0, f32x2{w0, w0});
            }
            // overflow edges (expected ~0-3 total per run)
            int no = *ovfcnt;
            if (no > 0) {
                if (no > OVFCAP) no = OVFCAP;
                for (int oi = 0; oi < no; ++oi) {
                    int4 ov = ovf[oi];
                    if (ov.x == row) {
                        uint4 u0 = *(const uint4*)(Xin + (size_t)ov.y * C + c0);
                        float w0 = rsqrtf((float)cnt[ov.y] + 1.0f)
                                 * bits2f((unsigned int)ov.z) * disr;
                        acc8(a, u0, f32x2{w0, w0});
                    }
                }
            }
        }
        ushort8_t pkt;
        #pragma unroll
        for (int q = 0; q < 4; ++q) { pkt[q * 2] = f2b(a[q].x); pkt[q * 2 + 1] = f2b(a[q].y); }
        int byte = (r * 256 + c0 * 2) ^ ((r & 7) << 4);
        *(ushort8_t*)((char*)xs + byte) = pkt;
    }
    __syncthreads();

    // phase B: 8-wave MFMA GEMM (32x128) = xs @ Wp; write f32 + bias into dacc
    {
        const int wm = wid >> 2;        // 0..1 (row tile of 16)
        const int wn = wid & 3;         // 0..3 (col quarter of 32)
        const int arow = wm * 16 + (lane & 15);
        const int kg = lane >> 4;

        f32x4 acc[2] = {f32x4{0, 0, 0, 0}, f32x4{0, 0, 0, 0}};

        #pragma unroll
        for (int ks = 0; ks < 4; ++ks) {
            int abyte = (arow * 256 + ks * 64 + kg * 16) ^ ((arow & 7) << 4);
            short8 av = *(const short8*)((const char*)xs + abyte);
            #pragma unroll
            for (int nt = 0; nt < 2; ++nt) {
                int ct = wn * 2 + nt;
                short8 bv = *(const short8*)(Wp + (size_t)((ct * 4 + ks) * 64 + lane) * 8);
                acc[nt] = __builtin_amdgcn_mfma_f32_16x16x32_bf16(av, bv, acc[nt], 0, 0, 0);
            }
        }

        const int rb = wm * 16 + kg * 4;   // block-local output row base
        #pragma unroll
        for (int nt = 0; nt < 2; ++nt) {
            int col = wn * 32 + nt * 16 + (lane & 15);
            float bv = bias[col];
            #pragma unroll
            for (int r2 = 0; r2 < 4; ++r2)
                dacc[(rb + r2) * DSTRIDE + col] = acc[nt][r2] + bv;
        }
    }
    __syncthreads();

    // phase C: LN + GELU per row from dacc (16 lanes/row), then epilogue
    {
        int r = wid * 4 + grp;
        int row = base + r;
        if (row >= n) return;

        const float* dp = dacc + r * DSTRIDE + c0;
        float4 v0 = *(const float4*)(dp);
        float4 v1 = *(const float4*)(dp + 4);
        float a[8] = {v0.x, v0.y, v0.z, v0.w, v1.x, v1.y, v1.z, v1.w};

        float s = 0.f, sq = 0.f;
        #pragma unroll
        for (int j = 0; j < 8; ++j) { s += a[j]; sq += a[j] * a[j]; }
        #pragma unroll
        for (int off = 8; off >= 1; off >>= 1) {
            s  += __shfl_xor(s, off, 64);
            sq += __shfl_xor(sq, off, 64);
        }
        float mu = s * (1.0f / C);
        float var = sq * (1.0f / C) - mu * mu;
        float rstd = rsqrtf(var + 1e-5f);

        float4 gv0 = *(const float4*)(g + c0);
        float4 gv1 = *(const float4*)(g + c0 + 4);
        float4 be0 = *(const float4*)(beta + c0);
        float4 be1 = *(const float4*)(beta + c0 + 4);
        float gg[8] = {gv0.x, gv0.y, gv0.z, gv0.w, gv1.x, gv1.y, gv1.z, gv1.w};
        float bb[8] = {be0.x, be0.y, be0.z, be0.w, be1.x, be1.y, be1.z, be1.w};

        float t[8];
        #pragma unroll
        for (int j = 0; j < 8; ++j) {
            float v = (a[j] - mu) * rstd * gg[j] + bb[j];
            t[j] = 0.5f * v * (1.0f + erff(v * 0.70710678118654752f));
        }

        if (out_f32 != nullptr) {
            ushort8_t rv = *(const ushort8_t*)(xb_resid + (size_t)row * C + c0);
            #pragma unroll
            for (int j = 0; j < 8; ++j)
                t[j] += bits2f(((unsigned int)(unsigned short)rv[j]) << 16);
            *(float4*)(out_f32 + (size_t)row * C + c0) = make_float4(t[0], t[1], t[2], t[3]);
            *(float4*)(out_f32 + (size_t)row * C + c0 + 4) = make_float4(t[4], t[5], t[6], t[7]);
        } else {
            ushort8_t pkt;
            #pragma unroll
            for (int j = 0; j < 8; ++j) pkt[j] = f2b(t[j]);
            *(ushort8_t*)(out_bf16 + (size_t)row * C + c0) = pkt;
        }
    }
}

// ================= launch =================

extern "C" void kernel_launch(void* const* d_in, const int* in_sizes, int n_in,
                              void* d_out, int out_size, void* d_ws, size_t ws_size,
                              hipStream_t stream) {
    const float* x      = (const float*)d_in[0];
    const int*   eidx   = (const int*)d_in[1];
    const float* ew     = (const float*)d_in[2];
    const float* W1     = (const float*)d_in[3];
    const float* b1     = (const float*)d_in[4];
    const float* g1     = (const float*)d_in[5];
    const float* beta1  = (const float*)d_in[6];
    const float* W2     = (const float*)d_in[7];
    const float* b2     = (const float*)d_in[8];
    const float* g2     = (const float*)d_in[9];
    const float* beta2  = (const float*)d_in[10];

    const int n = in_sizes[0] / C;
    const int e = in_sizes[2];
    const int* src = eidx;
    const int* dst = eidx + e;

    float* out = (float*)d_out;

    // workspace layout (256B-aligned chunks)
    char* p = (char*)d_ws;
    auto alloc = [&](size_t bytes) {
        char* q = p;
        p += (bytes + 255) & ~(size_t)255;
        return q;
    };
    int*   cnt    = (int*)alloc(sizeof(int) * (n + 1));           // cnt[n] = overflow count
    int2*  eslot  = (int2*)alloc(sizeof(int2) * (size_t)n * SLOTS);
    int4*  ovf    = (int4*)alloc(sizeof(int4) * OVFCAP);
    unsigned short* xb    = (unsigned short*)alloc(sizeof(unsigned short) * (size_t)n * C);
    unsigned short* hact1 = (unsigned short*)alloc(sizeof(unsigned short) * (size_t)n * C);
    unsigned short* W1p   = (unsigned short*)alloc(sizeof(unsigned short) * C * C);
    unsigned short* W2p   = (unsigned short*)alloc(sizeof(unsigned short) * C * C);
    int* ovfcnt = cnt + n;

    const int B = 256;
    const int ge4 = (e + 1023) / 1024;    // edge blocks (4 edges/thread)
    const int ncvt8 = n * C / 8;          // 8-elem convert items
    const int bc = (ncvt8 + B - 1) / B;   // convert blocks

    // prep: zero counters; then ONE kernel: edges (atomic-bound, starts at t=0) ||
    // weight-pack || x->bf16 convert (BW-bound, fills remaining CUs)
    hipMemsetAsync(cnt, 0, sizeof(int) * (n + 1), stream);
    k_place_cvt_pack<<<ge4 + 128 + bc, B, 0, stream>>>(src, dst, ew, cnt, ovfcnt,
                                                       eslot, ovf, e, ge4,
                                                       x, xb, ncvt8,
                                                       W1, W2, W1p, W2p);

    // layer 1: hact1 = GELU(LN(agg(xb) @ W1 + b1))
    k_layer<<<(n + 31) / 32, 512, 0, stream>>>(cnt, ovfcnt, eslot, ovf, xb, W1p,
                                               b1, g1, beta1, nullptr,
                                               hact1, nullptr, n);

    // layer 2: out = GELU(LN(agg(hact1) @ W2 + b2)) + x
    k_layer<<<(n + 31) / 32, 512, 0, stream>>>(cnt, ovfcnt, eslot, ovf, hact1, W2p,
                                               b2, g2, beta2, xb,
                                               nullptr, out, n);
}